// Round 1
// baseline (173.919 us; speedup 1.0000x reference)
//
#include <hip/hip_runtime.h>

// Problem: B=64, S=128, D_MODEL=D_INNER=1024  ->  M = B*S = 8192, K = N = 1024.
// Reference simplifies: numerator/denominator == v exactly (dw>0, exp_k>0 cancel),
// so out = (sigmoid(emb@Wq+bq) * (emb@Wv+bv)) @ Wo + bo.  Wk, bk, w are dead inputs.
//
// R7: structural change — both GEMMs moved from the m97 2-barrier single-buffer
// structure (MfmaUtil 28.5%, ~750 TF) to the phased counted-vmcnt schedule
// (T3+T4+T5 on top of existing T1 swizzle + T2 LDS swizzle):
//   BM=256 BN=128, 512 thr (8 waves, 4Mx2N), 2-slot LDS double buffer,
//   per-phase {ds_read -> s_barrier -> lgkmcnt(0) -> sched_barrier -> setprio(1)
//   -> 16 MFMA -> setprio(0) -> s_barrier}, vmcnt(8)/vmcnt(6) counted (never 0
//   mid-loop), stage tile j+2 after the trailing barrier (race-free), last iter
//   peeled with vmcnt(0).  Grid 256 = 1 block/CU for both GEMMs (bt was 512
//   blocks @ 2/CU with half the MFMA density; qv was 1024 @ 4/CU).

typedef short bf16x8 __attribute__((ext_vector_type(8)));  // 8 bf16 = 4 VGPRs
typedef float f32x4  __attribute__((ext_vector_type(4)));

__device__ __forceinline__ short f2bf(float f) {  // RNE fp32 -> bf16
  union { float f; unsigned u; } x; x.f = f;
  unsigned r = x.u + 0x7fffu + ((x.u >> 16) & 1u);
  return (short)(r >> 16);
}

struct alignas(16) S8 { short v[8]; };

#define GLDS(g, l) \
  __builtin_amdgcn_global_load_lds((const __attribute__((address_space(1))) void*)(g), \
                                   (__attribute__((address_space(3))) void*)(l), 16, 0, 0)
#define BAR()    __builtin_amdgcn_s_barrier()
#define PRIO(x)  __builtin_amdgcn_s_setprio(x)
#define SCHED0() __builtin_amdgcn_sched_barrier(0)
#define VMCNT(N) asm volatile("s_waitcnt vmcnt(" #N ")" ::: "memory")
#define LGKM0()  asm volatile("s_waitcnt lgkmcnt(0)" ::: "memory")
#define MFMA(a, b, c) __builtin_amdgcn_mfma_f32_16x16x32_bf16((a), (b), (c), 0, 0, 0)

// ---- Phase 0: emb fp32->bf16 + transpose/cast the three 1024x1024 weights ----
__global__ __launch_bounds__(256) void prep_kernel(
    const float* __restrict__ emb, const float* __restrict__ Wq, const float* __restrict__ Wv,
    const float* __restrict__ Wo, short* __restrict__ embB, short* __restrict__ WqvT,
    short* __restrict__ WoT) {
  __shared__ float tr[32 * 33];
  const int t = threadIdx.x;
  const int bid = blockIdx.x;
  const int gdim = gridDim.x;

  // emb cast: 1048576 groups of 8
  for (size_t i = (size_t)bid * 256 + t; i < 1048576; i += (size_t)gdim * 256) {
    const float4* p = (const float4*)emb + i * 2;
    float4 a = p[0], b = p[1];
    S8 s;
    s.v[0] = f2bf(a.x); s.v[1] = f2bf(a.y); s.v[2] = f2bf(a.z); s.v[3] = f2bf(a.w);
    s.v[4] = f2bf(b.x); s.v[5] = f2bf(b.y); s.v[6] = f2bf(b.z); s.v[7] = f2bf(b.w);
    ((S8*)embB)[i] = s;
  }

  // weight transposes: 3*1024 = 3072 32x32 tiles
  int tx = t & 31, ty = t >> 5;
  for (int z = bid; z < 3072; z += gdim) {
    const float* in = (z < 1024) ? Wq : (z < 2048) ? Wv : Wo;
    short* op = (z < 1024) ? WqvT : (z < 2048) ? (WqvT + 1048576) : WoT;
    int ti = z & 1023;
    int bx = (ti & 31) * 32, by = (ti >> 5) * 32;
    __syncthreads();  // protect LDS reuse across loop iterations
#pragma unroll
    for (int i = 0; i < 32; i += 8)
      tr[(ty + i) * 33 + tx] = in[(size_t)(by + ty + i) * 1024 + bx + tx];
    __syncthreads();
#pragma unroll
    for (int i = 0; i < 32; i += 8)
      op[(size_t)(bx + ty + i) * 1024 + by + tx] = f2bf(tr[tx * 33 + ty + i]);
  }
}

// ---- Phase 1: X = sigmoid(embB@WqT+bq) * (embB@WvT+bv), bf16. ----
// BM=256 BN=128, 8 waves (4Mx2N), each wave 64x64 of q AND v. 2-slot dbuf,
// 128 KiB LDS, 4 phases/K-tile, vmcnt(8) counted. grid 256 = 1 block/CU.
__global__ __launch_bounds__(512, 2) void gemm_qv_kernel(
    const short* __restrict__ A, const short* __restrict__ BT,  // BT=[WqT|WvT] 2048x1024
    const float* __restrict__ bq, const float* __restrict__ bv, short* __restrict__ X) {
  __shared__ short As[2][256 * 64];   // 64 KiB
  __shared__ short Bqs[2][128 * 64];  // 32 KiB
  __shared__ short Bvs[2][128 * 64];  // 32 KiB
  const int t = threadIdx.x;
  const int lane = t & 63;
  const int w = t >> 6;        // 0..7
  const int l16 = lane & 15;
  const int quad = lane >> 4;
  // XCD-aware mapping: 256 blocks, 8 XCDs -> each XCD gets 4 bm-groups x 8 bn
  const int b = blockIdx.x;
  const int wg = (b & 7) * 32 + (b >> 3);
  const int bm = (wg >> 3) * 256;
  const int bn = (wg & 7) * 128;
  const int wm = (w & 3) * 64;
  const int wn = (w >> 2) * 64;

  const int r8 = t >> 3;                        // 0..63: row within a 64-row stage chunk
  const int swe = ((t & 7) ^ (r8 & 7)) * 8;     // pre-swizzled global source chunk
  const short* gA = A + (size_t)(bm + r8) * 1024 + swe;
  const short* gq = BT + (size_t)(bn + r8) * 1024 + swe;
  const short* gv = BT + (size_t)(1024 + bn + r8) * 1024 + swe;
  short* lA = &As[0][0] + w * 512;   // wave-uniform base; HW adds lane*16B
  short* lq = &Bqs[0][0] + w * 512;
  short* lv = &Bvs[0][0] + w * 512;

#define QV_STAGE(k, s) do {                                             \
    const short* a_ = gA + (k) * 64; short* la_ = lA + (s) * 16384;     \
    GLDS(a_, la_);               GLDS(a_ + 64 * 1024, la_ + 4096);      \
    GLDS(a_ + 128 * 1024, la_ + 8192); GLDS(a_ + 192 * 1024, la_ + 12288); \
    const short* q_ = gq + (k) * 64; short* lq_ = lq + (s) * 8192;      \
    GLDS(q_, lq_);               GLDS(q_ + 64 * 1024, lq_ + 4096);      \
    const short* v_ = gv + (k) * 64; short* lv_ = lv + (s) * 8192;      \
    GLDS(v_, lv_);               GLDS(v_ + 64 * 1024, lv_ + 4096);      \
  } while (0)

  const int csw0 = (quad ^ (l16 & 7)) * 8;        // k-chunk quad   (k-half 0)
  const int csw1 = ((quad + 4) ^ (l16 & 7)) * 8;  // k-chunk quad+4 (k-half 1)
  const short* fA0 = &As[0][0] + (wm + l16) * 64 + csw0;
  const short* fA1 = &As[0][0] + (wm + l16) * 64 + csw1;
  const short* fq0 = &Bqs[0][0] + (wn + l16) * 64 + csw0;
  const short* fq1 = &Bqs[0][0] + (wn + l16) * 64 + csw1;
  const short* fv0 = &Bvs[0][0] + (wn + l16) * 64 + csw0;
  const short* fv1 = &Bvs[0][0] + (wn + l16) * 64 + csw1;

  f32x4 aq[4][4] = {};
  f32x4 av[4][4] = {};

  QV_STAGE(0, 0);
  QV_STAGE(1, 1);

  for (int j = 0; j < 16; ++j) {
    const int s = j & 1;
    const short* sA0 = fA0 + s * 16384;
    const short* sA1 = fA1 + s * 16384;
    const short* sq0 = fq0 + s * 8192;
    const short* sq1 = fq1 + s * 8192;
    const short* sv0 = fv0 + s * 8192;
    const short* sv1 = fv1 + s * 8192;

    // tile j landed iff only tile j+1's 8 loads remain (in-order retirement)
    if (j < 15) { VMCNT(8); } else { VMCNT(0); }
    BAR();

    bf16x8 a0[4], a1[4], b0[2], b1[2];
    // ---- phase 0: read all A frags + Bq cols 0-1; MFMA q n=0..1 ----
#pragma unroll
    for (int i = 0; i < 4; ++i) {
      a0[i] = *(const bf16x8*)(sA0 + i * 1024);
      a1[i] = *(const bf16x8*)(sA1 + i * 1024);
    }
    b0[0] = *(const bf16x8*)(sq0);        b0[1] = *(const bf16x8*)(sq0 + 1024);
    b1[0] = *(const bf16x8*)(sq1);        b1[1] = *(const bf16x8*)(sq1 + 1024);
    BAR(); LGKM0(); SCHED0(); PRIO(1);
#pragma unroll
    for (int i = 0; i < 4; ++i)
#pragma unroll
      for (int n = 0; n < 2; ++n) {
        aq[i][n] = MFMA(a0[i], b0[n], aq[i][n]);
        aq[i][n] = MFMA(a1[i], b1[n], aq[i][n]);
      }
    PRIO(0); BAR();
    // ---- phase 1: Bq cols 2-3; MFMA q n=2..3 ----
    b0[0] = *(const bf16x8*)(sq0 + 2048);  b0[1] = *(const bf16x8*)(sq0 + 3072);
    b1[0] = *(const bf16x8*)(sq1 + 2048);  b1[1] = *(const bf16x8*)(sq1 + 3072);
    BAR(); LGKM0(); SCHED0(); PRIO(1);
#pragma unroll
    for (int i = 0; i < 4; ++i)
#pragma unroll
      for (int n = 0; n < 2; ++n) {
        aq[i][2 + n] = MFMA(a0[i], b0[n], aq[i][2 + n]);
        aq[i][2 + n] = MFMA(a1[i], b1[n], aq[i][2 + n]);
      }
    PRIO(0); BAR();
    // ---- phase 2: Bv cols 0-1; MFMA v n=0..1 ----
    b0[0] = *(const bf16x8*)(sv0);         b0[1] = *(const bf16x8*)(sv0 + 1024);
    b1[0] = *(const bf16x8*)(sv1);         b1[1] = *(const bf16x8*)(sv1 + 1024);
    BAR(); LGKM0(); SCHED0(); PRIO(1);
#pragma unroll
    for (int i = 0; i < 4; ++i)
#pragma unroll
      for (int n = 0; n < 2; ++n) {
        av[i][n] = MFMA(a0[i], b0[n], av[i][n]);
        av[i][n] = MFMA(a1[i], b1[n], av[i][n]);
      }
    PRIO(0); BAR();
    // ---- phase 3: Bv cols 2-3; MFMA v n=2..3 ----
    b0[0] = *(const bf16x8*)(sv0 + 2048);  b0[1] = *(const bf16x8*)(sv0 + 3072);
    b1[0] = *(const bf16x8*)(sv1 + 2048);  b1[1] = *(const bf16x8*)(sv1 + 3072);
    BAR(); LGKM0(); SCHED0(); PRIO(1);
#pragma unroll
    for (int i = 0; i < 4; ++i)
#pragma unroll
      for (int n = 0; n < 2; ++n) {
        av[i][2 + n] = MFMA(a0[i], b0[n], av[i][2 + n]);
        av[i][2 + n] = MFMA(a1[i], b1[n], av[i][2 + n]);
      }
    PRIO(0); BAR();
    // all reads of slot s retired chip-wide (every wave passed lgkmcnt(0) before
    // its last MFMA, then the barrier) -> staging into slot s is race-free.
    if (j < 14) QV_STAGE(j + 2, s);
  }
#undef QV_STAGE

  // epilogue: C/D layout col=lane&15, row=(lane>>4)*4+reg  [m89/m91-verified]
#pragma unroll
  for (int n = 0; n < 4; ++n) {
    const int col = bn + wn + n * 16 + l16;
    const float bql = bq[col], bvl = bv[col];
#pragma unroll
    for (int i = 0; i < 4; ++i)
#pragma unroll
      for (int r = 0; r < 4; ++r) {
        const int row = bm + wm + i * 16 + quad * 4 + r;
        const float q = aq[i][n][r] + bql;
        const float v = av[i][n][r] + bvl;
        const float sg = 1.0f / (1.0f + __expf(-q));
        X[(size_t)row * 1024 + col] = f2bf(sg * v);
      }
  }
}

// ---- Phase 2: out = X @ WoT^T + bo, fp32. BM=256 BN=128, 8 waves (4Mx2N),
// each wave 64x64. 2-slot dbuf, 96 KiB LDS, 2 phases/K-tile, vmcnt(6). grid 256.
__global__ __launch_bounds__(512, 2) void gemm_bt_kernel(
    const short* __restrict__ A, const short* __restrict__ BT, float* __restrict__ C,
    const float* __restrict__ bias) {
  __shared__ short As[2][256 * 64];  // 64 KiB
  __shared__ short Bs[2][128 * 64];  // 32 KiB
  const int t = threadIdx.x;
  const int lane = t & 63;
  const int w = t >> 6;
  const int l16 = lane & 15;
  const int quad = lane >> 4;
  const int b = blockIdx.x;
  const int wg = (b & 7) * 32 + (b >> 3);
  const int bm = (wg >> 3) * 256;
  const int bn = (wg & 7) * 128;
  const int wm = (w & 3) * 64;
  const int wn = (w >> 2) * 64;

  const int r8 = t >> 3;
  const int swe = ((t & 7) ^ (r8 & 7)) * 8;
  const short* gA = A + (size_t)(bm + r8) * 1024 + swe;
  const short* gB = BT + (size_t)(bn + r8) * 1024 + swe;
  short* lA = &As[0][0] + w * 512;
  short* lB = &Bs[0][0] + w * 512;

#define BT_STAGE(k, s) do {                                             \
    const short* a_ = gA + (k) * 64; short* la_ = lA + (s) * 16384;     \
    GLDS(a_, la_);               GLDS(a_ + 64 * 1024, la_ + 4096);      \
    GLDS(a_ + 128 * 1024, la_ + 8192); GLDS(a_ + 192 * 1024, la_ + 12288); \
    const short* b_ = gB + (k) * 64; short* lb_ = lB + (s) * 8192;      \
    GLDS(b_, lb_);               GLDS(b_ + 64 * 1024, lb_ + 4096);      \
  } while (0)

  const int csw0 = (quad ^ (l16 & 7)) * 8;
  const int csw1 = ((quad + 4) ^ (l16 & 7)) * 8;
  const short* fA0 = &As[0][0] + (wm + l16) * 64 + csw0;
  const short* fA1 = &As[0][0] + (wm + l16) * 64 + csw1;
  const short* fB0 = &Bs[0][0] + (wn + l16) * 64 + csw0;
  const short* fB1 = &Bs[0][0] + (wn + l16) * 64 + csw1;

  f32x4 acc[4][4] = {};

  BT_STAGE(0, 0);
  BT_STAGE(1, 1);

  for (int j = 0; j < 16; ++j) {
    const int s = j & 1;
    const short* sA0 = fA0 + s * 16384;
    const short* sA1 = fA1 + s * 16384;
    const short* sB0 = fB0 + s * 8192;
    const short* sB1 = fB1 + s * 8192;

    if (j < 15) { VMCNT(6); } else { VMCNT(0); }
    BAR();

    bf16x8 a0[4], a1[4], b0[2], b1[2];
    // ---- phase 0: read all A frags + B cols 0-1; MFMA n=0..1 ----
#pragma unroll
    for (int i = 0; i < 4; ++i) {
      a0[i] = *(const bf16x8*)(sA0 + i * 1024);
      a1[i] = *(const bf16x8*)(sA1 + i * 1024);
    }
    b0[0] = *(const bf16x8*)(sB0);        b0[1] = *(const bf16x8*)(sB0 + 1024);
    b1[0] = *(const bf16x8*)(sB1);        b1[1] = *(const bf16x8*)(sB1 + 1024);
    BAR(); LGKM0(); SCHED0(); PRIO(1);
#pragma unroll
    for (int i = 0; i < 4; ++i)
#pragma unroll
      for (int n = 0; n < 2; ++n) {
        acc[i][n] = MFMA(a0[i], b0[n], acc[i][n]);
        acc[i][n] = MFMA(a1[i], b1[n], acc[i][n]);
      }
    PRIO(0); BAR();
    // ---- phase 1: B cols 2-3; MFMA n=2..3 ----
    b0[0] = *(const bf16x8*)(sB0 + 2048);  b0[1] = *(const bf16x8*)(sB0 + 3072);
    b1[0] = *(const bf16x8*)(sB1 + 2048);  b1[1] = *(const bf16x8*)(sB1 + 3072);
    BAR(); LGKM0(); SCHED0(); PRIO(1);
#pragma unroll
    for (int i = 0; i < 4; ++i)
#pragma unroll
      for (int n = 0; n < 2; ++n) {
        acc[i][2 + n] = MFMA(a0[i], b0[n], acc[i][2 + n]);
        acc[i][2 + n] = MFMA(a1[i], b1[n], acc[i][2 + n]);
      }
    PRIO(0); BAR();
    if (j < 14) BT_STAGE(j + 2, s);
  }
#undef BT_STAGE

#pragma unroll
  for (int n = 0; n < 4; ++n) {
    const int col = bn + wn + n * 16 + l16;
    const float bl = bias[col];
#pragma unroll
    for (int i = 0; i < 4; ++i)
#pragma unroll
      for (int r = 0; r < 4; ++r) {
        const int row = bm + wm + i * 16 + quad * 4 + r;
        C[(size_t)row * 1024 + col] = acc[i][n][r] + bl;
      }
  }
}

extern "C" void kernel_launch(void* const* d_in, const int* in_sizes, int n_in,
                              void* d_out, int out_size, void* d_ws, size_t ws_size,
                              hipStream_t stream) {
  const float* emb = (const float*)d_in[0];
  const float* Wq  = (const float*)d_in[1];
  const float* bq  = (const float*)d_in[2];
  // d_in[3]=Wk, d_in[4]=bk, d_in[7]=w are mathematically dead (they cancel)
  const float* Wv  = (const float*)d_in[5];
  const float* bv  = (const float*)d_in[6];
  const float* Wo  = (const float*)d_in[8];
  const float* bo  = (const float*)d_in[9];
  float* out = (float*)d_out;

  // workspace layout (bytes)
  char* ws = (char*)d_ws;
  short* embB = (short*)(ws);                 // 8192*1024 bf16 = 16 MiB
  short* X    = (short*)(ws + 16777216);      // 8192*1024 bf16 = 16 MiB
  short* WqvT = (short*)(ws + 33554432);      // [WqT | WvT] 2048*1024 = 4 MiB
  short* WoT  = (short*)(ws + 37748736);      // 1024*1024 = 2 MiB
  // total: 39,845,888 bytes

  prep_kernel<<<1024, 256, 0, stream>>>(emb, Wq, Wv, Wo, embB, WqvT, WoT);
  gemm_qv_kernel<<<256, 512, 0, stream>>>(embB, WqvT, bq, bv, X);
  gemm_bt_kernel<<<256, 512, 0, stream>>>(X, WoT, out, bo);
}

// Round 2
// 167.712 us; speedup vs baseline: 1.0370x; 1.0370x over previous
//
#include <hip/hip_runtime.h>

// Problem: B=64, S=128, D_MODEL=D_INNER=1024  ->  M = B*S = 8192, K = N = 1024.
// Reference simplifies: numerator/denominator == v exactly (dw>0, exp_k>0 cancel),
// so out = (sigmoid(emb@Wq+bq) * (emb@Wv+bv)) @ Wo + bo.  Wk, bk, w are dead inputs.
//
// R8: two changes, one per bottleneck half.
// (a) GEMM K-loop restructured for the m196-causal fine interleave: all ds_reads
//     of slot s land in phases 0-1 (12/12), slot s is free at ph1's barrier, and
//     the 8 (qv) / 6 (bt) global_load_lds for tile j+2 are spread across phases
//     2-3 *between* MFMA clusters (race-free: every wave passed ph1's
//     lgkmcnt(0)+barrier before any GLDS into s). vmcnt stays counted (8/6),
//     never 0 mid-loop. Barriers: 6/K-tile (was 8).
// (b) prep rewritten: 64x64 transpose tiles, float4 row reads (256B runs),
//     LDS pad 65, short8 transposed stores (128B runs), grid 256 = 1 round.

typedef short bf16x8 __attribute__((ext_vector_type(8)));  // 8 bf16 = 4 VGPRs
typedef float f32x4  __attribute__((ext_vector_type(4)));

__device__ __forceinline__ short f2bf(float f) {  // RNE fp32 -> bf16
  union { float f; unsigned u; } x; x.f = f;
  unsigned r = x.u + 0x7fffu + ((x.u >> 16) & 1u);
  return (short)(r >> 16);
}

struct alignas(16) S8 { short v[8]; };

#define GLDS(g, l) \
  __builtin_amdgcn_global_load_lds((const __attribute__((address_space(1))) void*)(g), \
                                   (__attribute__((address_space(3))) void*)(l), 16, 0, 0)
#define BAR()    __builtin_amdgcn_s_barrier()
#define PRIO(x)  __builtin_amdgcn_s_setprio(x)
#define SCHED0() __builtin_amdgcn_sched_barrier(0)
#define VMCNT(N) asm volatile("s_waitcnt vmcnt(" #N ")" ::: "memory")
#define LGKM0()  asm volatile("s_waitcnt lgkmcnt(0)" ::: "memory")
#define MFMA(a, b, c) __builtin_amdgcn_mfma_f32_16x16x32_bf16((a), (b), (c), 0, 0, 0)

// ---- Phase 0: emb fp32->bf16 + transpose/cast the three 1024x1024 weights ----
// grid 256 (1/CU, one round). Transpose: 64x64 tiles, 768 total, 3 per block.
__global__ __launch_bounds__(256) void prep_kernel(
    const float* __restrict__ emb, const float* __restrict__ Wq, const float* __restrict__ Wv,
    const float* __restrict__ Wo, short* __restrict__ embB, short* __restrict__ WqvT,
    short* __restrict__ WoT) {
  __shared__ float tr[64 * 65];  // 16.6 KiB, pad 65 breaks column-read conflicts
  const int t = threadIdx.x;
  const int bid = blockIdx.x;
  const int gdim = gridDim.x;

  // emb cast: 1048576 groups of 8 floats -> 8 bf16 (16 iters/thread at grid 256)
  for (size_t i = (size_t)bid * 256 + t; i < 1048576; i += (size_t)gdim * 256) {
    const float4* p = (const float4*)emb + i * 2;
    float4 a = p[0], b = p[1];
    S8 s;
    s.v[0] = f2bf(a.x); s.v[1] = f2bf(a.y); s.v[2] = f2bf(a.z); s.v[3] = f2bf(a.w);
    s.v[4] = f2bf(b.x); s.v[5] = f2bf(b.y); s.v[6] = f2bf(b.z); s.v[7] = f2bf(b.w);
    ((S8*)embB)[i] = s;
  }

  // weight transposes: 3 * 256 = 768 tiles of 64x64
  const int rr = t >> 4, cc4 = (t & 15) * 4;     // read coords
  const int orow = t >> 3, ocol8 = (t & 7) * 8;  // write coords
  for (int z = bid; z < 768; z += gdim) {
    const float* in; short* op; int ti;
    if (z < 256)      { in = Wq; op = WqvT;           ti = z; }
    else if (z < 512) { in = Wv; op = WqvT + 1048576; ti = z - 256; }
    else              { in = Wo; op = WoT;            ti = z - 512; }
    const int bx = (ti & 15) * 64, by = (ti >> 4) * 64;
    __syncthreads();  // protect LDS reuse across z-iterations
#pragma unroll
    for (int k = 0; k < 4; ++k) {
      float4 v = *(const float4*)&in[(size_t)(by + rr + 16 * k) * 1024 + bx + cc4];
      float* d = &tr[(rr + 16 * k) * 65 + cc4];
      d[0] = v.x; d[1] = v.y; d[2] = v.z; d[3] = v.w;
    }
    __syncthreads();
#pragma unroll
    for (int h = 0; h < 2; ++h) {
      const int oc = orow + 32 * h;  // output row within tile = input col
      S8 s;
#pragma unroll
      for (int i = 0; i < 8; ++i) s.v[i] = f2bf(tr[(ocol8 + i) * 65 + oc]);
      *(S8*)&op[(size_t)(bx + oc) * 1024 + by + ocol8] = s;  // 16B, 128B runs
    }
  }
}

// ---- Phase 1: X = sigmoid(embB@WqT+bq) * (embB@WvT+bv), bf16. ----
// BM=256 BN=128 (q AND v), 8 waves 4Mx2N, wave 64x64 q + 64x64 v. 2-slot dbuf,
// 128 KiB. Phases: ph0 reads 12 / MFMA q-k0; ph1 reads 12 / MFMA q-k1;
// ph2 GLDS 4 / MFMA v-k0; ph3 GLDS 4 / MFMA v-k1. vmcnt(8) counted. grid 256.
__global__ __launch_bounds__(512, 2) void gemm_qv_kernel(
    const short* __restrict__ A, const short* __restrict__ BT,  // BT=[WqT|WvT] 2048x1024
    const float* __restrict__ bq, const float* __restrict__ bv, short* __restrict__ X) {
  __shared__ short As[2][256 * 64];   // 64 KiB
  __shared__ short Bqs[2][128 * 64];  // 32 KiB
  __shared__ short Bvs[2][128 * 64];  // 32 KiB
  const int t = threadIdx.x;
  const int lane = t & 63;
  const int w = t >> 6;        // 0..7
  const int l16 = lane & 15;
  const int quad = lane >> 4;
  const int b = blockIdx.x;
  const int wg = (b & 7) * 32 + (b >> 3);  // bijective XCD swizzle (256%8==0)
  const int bm = (wg >> 3) * 256;
  const int bn = (wg & 7) * 128;
  const int wm = (w & 3) * 64;
  const int wn = (w >> 2) * 64;

  const int r8 = t >> 3;                        // 0..63: row within a 64-row chunk
  const int swe = ((t & 7) ^ (r8 & 7)) * 8;     // pre-swizzled global source chunk
  const short* gA = A + (size_t)(bm + r8) * 1024 + swe;
  const short* gq = BT + (size_t)(bn + r8) * 1024 + swe;
  const short* gv = BT + (size_t)(1024 + bn + r8) * 1024 + swe;
  short* lA = &As[0][0] + w * 512;   // wave-uniform base; HW adds lane*16B
  short* lq = &Bqs[0][0] + w * 512;
  short* lv = &Bvs[0][0] + w * 512;

  // full-tile stage (prologue only)
#define QV_STAGE(k, s) do {                                             \
    const short* a_ = gA + (k) * 64; short* la_ = lA + (s) * 16384;     \
    GLDS(a_, la_);               GLDS(a_ + 64 * 1024, la_ + 4096);      \
    GLDS(a_ + 128 * 1024, la_ + 8192); GLDS(a_ + 192 * 1024, la_ + 12288); \
    const short* q_ = gq + (k) * 64; short* lq_ = lq + (s) * 8192;      \
    GLDS(q_, lq_);               GLDS(q_ + 64 * 1024, lq_ + 4096);      \
    const short* v_ = gv + (k) * 64; short* lv_ = lv + (s) * 8192;      \
    GLDS(v_, lv_);               GLDS(v_ + 64 * 1024, lv_ + 4096);      \
  } while (0)

  const int csw0 = (quad ^ (l16 & 7)) * 8;        // k-chunk quad   (k-half 0)
  const int csw1 = ((quad + 4) ^ (l16 & 7)) * 8;  // k-chunk quad+4 (k-half 1)
  const short* fA0 = &As[0][0] + (wm + l16) * 64 + csw0;
  const short* fA1 = &As[0][0] + (wm + l16) * 64 + csw1;
  const short* fq0 = &Bqs[0][0] + (wn + l16) * 64 + csw0;
  const short* fq1 = &Bqs[0][0] + (wn + l16) * 64 + csw1;
  const short* fv0 = &Bvs[0][0] + (wn + l16) * 64 + csw0;
  const short* fv1 = &Bvs[0][0] + (wn + l16) * 64 + csw1;

  f32x4 aq[4][4] = {};
  f32x4 av[4][4] = {};

  QV_STAGE(0, 0);
  QV_STAGE(1, 1);

  for (int j = 0; j < 16; ++j) {
    const int s = j & 1;
    const short* sA0 = fA0 + s * 16384;
    const short* sA1 = fA1 + s * 16384;
    const short* sq0 = fq0 + s * 8192;
    const short* sq1 = fq1 + s * 8192;
    const short* sv0 = fv0 + s * 8192;
    const short* sv1 = fv1 + s * 8192;

    // tile j landed iff only tile j+1's 8 loads remain (in-order retirement)
    if (j < 15) { VMCNT(8); } else { VMCNT(0); }
    BAR();

    bf16x8 a0[4], a1[4], bq0[4], bq1[4], bv0[4], bv1[4];
    // ---- ph0: read A (both k-halves) + Bq k-half0 (12 reads); MFMA q k0 ----
#pragma unroll
    for (int i = 0; i < 4; ++i) {
      a0[i] = *(const bf16x8*)(sA0 + i * 1024);
      a1[i] = *(const bf16x8*)(sA1 + i * 1024);
      bq0[i] = *(const bf16x8*)(sq0 + i * 1024);
    }
    BAR(); LGKM0(); SCHED0(); PRIO(1);
#pragma unroll
    for (int i = 0; i < 4; ++i)
#pragma unroll
      for (int n = 0; n < 4; ++n)
        aq[i][n] = MFMA(a0[i], bq0[n], aq[i][n]);
    PRIO(0); BAR();
    // ---- ph1: read Bq k1 + Bv k0 + Bv k1 (12 reads); MFMA q k1 ----
#pragma unroll
    for (int i = 0; i < 4; ++i) {
      bq1[i] = *(const bf16x8*)(sq1 + i * 1024);
      bv0[i] = *(const bf16x8*)(sv0 + i * 1024);
      bv1[i] = *(const bf16x8*)(sv1 + i * 1024);
    }
    BAR(); LGKM0(); SCHED0(); PRIO(1);
#pragma unroll
    for (int i = 0; i < 4; ++i)
#pragma unroll
      for (int n = 0; n < 4; ++n)
        aq[i][n] = MFMA(a1[i], bq1[n], aq[i][n]);
    PRIO(0); BAR();
    // slot s fully consumed chip-wide (every wave drained lgkmcnt(0) then hit
    // the barrier) -> staging tile j+2 into slot s below is race-free.
    // ---- ph2: GLDS A of tile j+2 (4) interleaved with MFMA v k0 ----
    if (j < 14) {
      const short* a_ = gA + (j + 2) * 64; short* la_ = lA + s * 16384;
      GLDS(a_, la_);                     GLDS(a_ + 64 * 1024, la_ + 4096);
      GLDS(a_ + 128 * 1024, la_ + 8192); GLDS(a_ + 192 * 1024, la_ + 12288);
    }
    PRIO(1);
#pragma unroll
    for (int i = 0; i < 4; ++i)
#pragma unroll
      for (int n = 0; n < 4; ++n)
        av[i][n] = MFMA(a0[i], bv0[n], av[i][n]);
    PRIO(0); BAR();
    // ---- ph3: GLDS Bq,Bv of tile j+2 (4) interleaved with MFMA v k1 ----
    if (j < 14) {
      const short* q_ = gq + (j + 2) * 64; short* lq_ = lq + s * 8192;
      GLDS(q_, lq_); GLDS(q_ + 64 * 1024, lq_ + 4096);
      const short* v_ = gv + (j + 2) * 64; short* lv_ = lv + s * 8192;
      GLDS(v_, lv_); GLDS(v_ + 64 * 1024, lv_ + 4096);
    }
    PRIO(1);
#pragma unroll
    for (int i = 0; i < 4; ++i)
#pragma unroll
      for (int n = 0; n < 4; ++n)
        av[i][n] = MFMA(a1[i], bv1[n], av[i][n]);
    PRIO(0); BAR();
  }
#undef QV_STAGE

  // epilogue: C/D layout col=lane&15, row=(lane>>4)*4+reg  [m89/m91-verified]
#pragma unroll
  for (int n = 0; n < 4; ++n) {
    const int col = bn + wn + n * 16 + l16;
    const float bql = bq[col], bvl = bv[col];
#pragma unroll
    for (int i = 0; i < 4; ++i)
#pragma unroll
      for (int r = 0; r < 4; ++r) {
        const int row = bm + wm + i * 16 + quad * 4 + r;
        const float q = aq[i][n][r] + bql;
        const float v = av[i][n][r] + bvl;
        const float sg = 1.0f / (1.0f + __expf(-q));
        X[(size_t)row * 1024 + col] = f2bf(sg * v);
      }
  }
}

// ---- Phase 2: out = X @ WoT^T + bo, fp32. BM=256 BN=128, 8 waves 4Mx2N,
// wave 64x64. 2-slot dbuf, 96 KiB. Phases: ph0 reads 12 / 8 MFMA; ph1 reads 4 /
// 8 MFMA; ph2 GLDS 3 / 8 MFMA; ph3 GLDS 3 / 8 MFMA. vmcnt(6). grid 256.
__global__ __launch_bounds__(512, 2) void gemm_bt_kernel(
    const short* __restrict__ A, const short* __restrict__ BT, float* __restrict__ C,
    const float* __restrict__ bias) {
  __shared__ short As[2][256 * 64];  // 64 KiB
  __shared__ short Bs[2][128 * 64];  // 32 KiB
  const int t = threadIdx.x;
  const int lane = t & 63;
  const int w = t >> 6;
  const int l16 = lane & 15;
  const int quad = lane >> 4;
  const int b = blockIdx.x;
  const int wg = (b & 7) * 32 + (b >> 3);
  const int bm = (wg >> 3) * 256;
  const int bn = (wg & 7) * 128;
  const int wm = (w & 3) * 64;
  const int wn = (w >> 2) * 64;

  const int r8 = t >> 3;
  const int swe = ((t & 7) ^ (r8 & 7)) * 8;
  const short* gA = A + (size_t)(bm + r8) * 1024 + swe;
  const short* gB = BT + (size_t)(bn + r8) * 1024 + swe;
  short* lA = &As[0][0] + w * 512;
  short* lB = &Bs[0][0] + w * 512;

#define BT_STAGE(k, s) do {                                             \
    const short* a_ = gA + (k) * 64; short* la_ = lA + (s) * 16384;     \
    GLDS(a_, la_);               GLDS(a_ + 64 * 1024, la_ + 4096);      \
    GLDS(a_ + 128 * 1024, la_ + 8192); GLDS(a_ + 192 * 1024, la_ + 12288); \
    const short* b_ = gB + (k) * 64; short* lb_ = lB + (s) * 8192;      \
    GLDS(b_, lb_);               GLDS(b_ + 64 * 1024, lb_ + 4096);      \
  } while (0)

  const int csw0 = (quad ^ (l16 & 7)) * 8;
  const int csw1 = ((quad + 4) ^ (l16 & 7)) * 8;
  const short* fA0 = &As[0][0] + (wm + l16) * 64 + csw0;
  const short* fA1 = &As[0][0] + (wm + l16) * 64 + csw1;
  const short* fB0 = &Bs[0][0] + (wn + l16) * 64 + csw0;
  const short* fB1 = &Bs[0][0] + (wn + l16) * 64 + csw1;

  f32x4 acc[4][4] = {};

  BT_STAGE(0, 0);
  BT_STAGE(1, 1);

  for (int j = 0; j < 16; ++j) {
    const int s = j & 1;
    const short* sA0 = fA0 + s * 16384;
    const short* sA1 = fA1 + s * 16384;
    const short* sB0 = fB0 + s * 8192;
    const short* sB1 = fB1 + s * 8192;

    if (j < 15) { VMCNT(6); } else { VMCNT(0); }
    BAR();

    bf16x8 a0[4], a1[4], b0[4], b1[4];
    // ---- ph0: read A (both halves) + B k0 (12); MFMA k0 n0-1 ----
#pragma unroll
    for (int i = 0; i < 4; ++i) {
      a0[i] = *(const bf16x8*)(sA0 + i * 1024);
      a1[i] = *(const bf16x8*)(sA1 + i * 1024);
      b0[i] = *(const bf16x8*)(sB0 + i * 1024);
    }
    BAR(); LGKM0(); SCHED0(); PRIO(1);
#pragma unroll
    for (int i = 0; i < 4; ++i)
#pragma unroll
      for (int n = 0; n < 2; ++n)
        acc[i][n] = MFMA(a0[i], b0[n], acc[i][n]);
    PRIO(0); BAR();
    // ---- ph1: read B k1 (4); MFMA k0 n2-3 ----
#pragma unroll
    for (int i = 0; i < 4; ++i) b1[i] = *(const bf16x8*)(sB1 + i * 1024);
    BAR(); LGKM0(); SCHED0(); PRIO(1);
#pragma unroll
    for (int i = 0; i < 4; ++i)
#pragma unroll
      for (int n = 0; n < 2; ++n)
        acc[i][2 + n] = MFMA(a0[i], b0[2 + n], acc[i][2 + n]);
    PRIO(0); BAR();
    // slot s free; stage tile j+2 spread across ph2/ph3
    // ---- ph2: GLDS A part (3) + MFMA k1 n0-1 ----
    if (j < 14) {
      const short* a_ = gA + (j + 2) * 64; short* la_ = lA + s * 16384;
      GLDS(a_, la_); GLDS(a_ + 64 * 1024, la_ + 4096);
      GLDS(a_ + 128 * 1024, la_ + 8192);
    }
    PRIO(1);
#pragma unroll
    for (int i = 0; i < 4; ++i)
#pragma unroll
      for (int n = 0; n < 2; ++n)
        acc[i][n] = MFMA(a1[i], b1[n], acc[i][n]);
    PRIO(0); BAR();
    // ---- ph3: GLDS A tail + B (3) + MFMA k1 n2-3 ----
    if (j < 14) {
      const short* a_ = gA + (j + 2) * 64; short* la_ = lA + s * 16384;
      GLDS(a_ + 192 * 1024, la_ + 12288);
      const short* b_ = gB + (j + 2) * 64; short* lb_ = lB + s * 8192;
      GLDS(b_, lb_); GLDS(b_ + 64 * 1024, lb_ + 4096);
    }
    PRIO(1);
#pragma unroll
    for (int i = 0; i < 4; ++i)
#pragma unroll
      for (int n = 0; n < 2; ++n)
        acc[i][2 + n] = MFMA(a1[i], b1[2 + n], acc[i][2 + n]);
    PRIO(0); BAR();
  }
#undef BT_STAGE

#pragma unroll
  for (int n = 0; n < 4; ++n) {
    const int col = bn + wn + n * 16 + l16;
    const float bl = bias[col];
#pragma unroll
    for (int i = 0; i < 4; ++i)
#pragma unroll
      for (int r = 0; r < 4; ++r) {
        const int row = bm + wm + i * 16 + quad * 4 + r;
        C[(size_t)row * 1024 + col] = acc[i][n][r] + bl;
      }
  }
}

extern "C" void kernel_launch(void* const* d_in, const int* in_sizes, int n_in,
                              void* d_out, int out_size, void* d_ws, size_t ws_size,
                              hipStream_t stream) {
  const float* emb = (const float*)d_in[0];
  const float* Wq  = (const float*)d_in[1];
  const float* bq  = (const float*)d_in[2];
  // d_in[3]=Wk, d_in[4]=bk, d_in[7]=w are mathematically dead (they cancel)
  const float* Wv  = (const float*)d_in[5];
  const float* bv  = (const float*)d_in[6];
  const float* Wo  = (const float*)d_in[8];
  const float* bo  = (const float*)d_in[9];
  float* out = (float*)d_out;

  // workspace layout (bytes)
  char* ws = (char*)d_ws;
  short* embB = (short*)(ws);                 // 8192*1024 bf16 = 16 MiB
  short* X    = (short*)(ws + 16777216);      // 8192*1024 bf16 = 16 MiB
  short* WqvT = (short*)(ws + 33554432);      // [WqT | WvT] 2048*1024 = 4 MiB
  short* WoT  = (short*)(ws + 37748736);      // 1024*1024 = 2 MiB
  // total: 39,845,888 bytes

  prep_kernel<<<256, 256, 0, stream>>>(emb, Wq, Wv, Wo, embB, WqvT, WoT);
  gemm_qv_kernel<<<256, 512, 0, stream>>>(embB, WqvT, bq, bv, X);
  gemm_bt_kernel<<<256, 512, 0, stream>>>(X, WoT, out, bo);
}

// Round 3
// 162.188 us; speedup vs baseline: 1.0723x; 1.0341x over previous
//
#include <hip/hip_runtime.h>

// Problem: B=64, S=128, D_MODEL=D_INNER=1024  ->  M = B*S = 8192, K = N = 1024.
// Reference simplifies: numerator/denominator == v exactly (dw>0, exp_k>0 cancel),
// so out = (sigmoid(emb@Wq+bq) * (emb@Wv+bv)) @ Wo + bo.  Wk, bk, w are dead inputs.
//
// R9: attribution round.
// - qv: KEEP R8 phased structure (measured 40.9us, 840 TF — best so far).
// - bt: REVERT to R0-proven 128x128 / 256thr / 32KiB / grid 512 (2 blocks/CU)
//   m97 structure. Cross-round A/B showed bt-phased@1-block/CU cost ~4.5us vs
//   this: bt is staging-heavy per FLOP and needs inter-block TLP, not phases.
// - prep: grid 768 (one 64x64 transpose tile per block; cast in ~5 strided its).
// Known fixed cost: harness re-poison fills 256MiB@41us/rep (top dispatch) —
// not controllable from kernel source.

typedef short bf16x8 __attribute__((ext_vector_type(8)));  // 8 bf16 = 4 VGPRs
typedef float f32x4  __attribute__((ext_vector_type(4)));

__device__ __forceinline__ short f2bf(float f) {  // RNE fp32 -> bf16
  union { float f; unsigned u; } x; x.f = f;
  unsigned r = x.u + 0x7fffu + ((x.u >> 16) & 1u);
  return (short)(r >> 16);
}

struct alignas(16) S8 { short v[8]; };

#define GLDS(g, l) \
  __builtin_amdgcn_global_load_lds((const __attribute__((address_space(1))) void*)(g), \
                                   (__attribute__((address_space(3))) void*)(l), 16, 0, 0)
#define BAR()    __builtin_amdgcn_s_barrier()
#define PRIO(x)  __builtin_amdgcn_s_setprio(x)
#define SCHED0() __builtin_amdgcn_sched_barrier(0)
#define VMCNT(N) asm volatile("s_waitcnt vmcnt(" #N ")" ::: "memory")
#define LGKM0()  asm volatile("s_waitcnt lgkmcnt(0)" ::: "memory")
#define MFMA(a, b, c) __builtin_amdgcn_mfma_f32_16x16x32_bf16((a), (b), (c), 0, 0, 0)

// ---- Phase 0: emb fp32->bf16 + transpose/cast the three 1024x1024 weights ----
// grid 768: one 64x64 transpose tile per block; cast strided (~5.3 its/thread).
__global__ __launch_bounds__(256) void prep_kernel(
    const float* __restrict__ emb, const float* __restrict__ Wq, const float* __restrict__ Wv,
    const float* __restrict__ Wo, short* __restrict__ embB, short* __restrict__ WqvT,
    short* __restrict__ WoT) {
  __shared__ float tr[64 * 65];  // 16.6 KiB, pad 65 breaks column-read conflicts
  const int t = threadIdx.x;
  const int bid = blockIdx.x;
  const int gdim = gridDim.x;

  // emb cast: 1048576 groups of 8 floats -> 8 bf16
  for (size_t i = (size_t)bid * 256 + t; i < 1048576; i += (size_t)gdim * 256) {
    const float4* p = (const float4*)emb + i * 2;
    float4 a = p[0], b = p[1];
    S8 s;
    s.v[0] = f2bf(a.x); s.v[1] = f2bf(a.y); s.v[2] = f2bf(a.z); s.v[3] = f2bf(a.w);
    s.v[4] = f2bf(b.x); s.v[5] = f2bf(b.y); s.v[6] = f2bf(b.z); s.v[7] = f2bf(b.w);
    ((S8*)embB)[i] = s;
  }

  // weight transposes: 3 * 256 = 768 tiles of 64x64 (one per block at grid 768)
  const int rr = t >> 4, cc4 = (t & 15) * 4;     // read coords
  const int orow = t >> 3, ocol8 = (t & 7) * 8;  // write coords
  for (int z = bid; z < 768; z += gdim) {
    const float* in; short* op; int ti;
    if (z < 256)      { in = Wq; op = WqvT;           ti = z; }
    else if (z < 512) { in = Wv; op = WqvT + 1048576; ti = z - 256; }
    else              { in = Wo; op = WoT;            ti = z - 512; }
    const int bx = (ti & 15) * 64, by = (ti >> 4) * 64;
    __syncthreads();  // protect LDS reuse across z-iterations
#pragma unroll
    for (int k = 0; k < 4; ++k) {
      float4 v = *(const float4*)&in[(size_t)(by + rr + 16 * k) * 1024 + bx + cc4];
      float* d = &tr[(rr + 16 * k) * 65 + cc4];
      d[0] = v.x; d[1] = v.y; d[2] = v.z; d[3] = v.w;
    }
    __syncthreads();
#pragma unroll
    for (int h = 0; h < 2; ++h) {
      const int oc = orow + 32 * h;  // output row within tile = input col
      S8 s;
#pragma unroll
      for (int i = 0; i < 8; ++i) s.v[i] = f2bf(tr[(ocol8 + i) * 65 + oc]);
      *(S8*)&op[(size_t)(bx + oc) * 1024 + by + ocol8] = s;  // 16B, 128B runs
    }
  }
}

// ---- Phase 1: X = sigmoid(embB@WqT+bq) * (embB@WvT+bv), bf16. ----
// R8 structure, unchanged (measured 40.9us). BM=256 BN=128, 8 waves 4Mx2N,
// 2-slot dbuf 128 KiB, 4 phases/K-tile, GLDS spread over ph2/ph3, vmcnt(8).
__global__ __launch_bounds__(512, 2) void gemm_qv_kernel(
    const short* __restrict__ A, const short* __restrict__ BT,  // BT=[WqT|WvT] 2048x1024
    const float* __restrict__ bq, const float* __restrict__ bv, short* __restrict__ X) {
  __shared__ short As[2][256 * 64];   // 64 KiB
  __shared__ short Bqs[2][128 * 64];  // 32 KiB
  __shared__ short Bvs[2][128 * 64];  // 32 KiB
  const int t = threadIdx.x;
  const int lane = t & 63;
  const int w = t >> 6;        // 0..7
  const int l16 = lane & 15;
  const int quad = lane >> 4;
  const int b = blockIdx.x;
  const int wg = (b & 7) * 32 + (b >> 3);  // bijective XCD swizzle (256%8==0)
  const int bm = (wg >> 3) * 256;
  const int bn = (wg & 7) * 128;
  const int wm = (w & 3) * 64;
  const int wn = (w >> 2) * 64;

  const int r8 = t >> 3;                        // 0..63: row within a 64-row chunk
  const int swe = ((t & 7) ^ (r8 & 7)) * 8;     // pre-swizzled global source chunk
  const short* gA = A + (size_t)(bm + r8) * 1024 + swe;
  const short* gq = BT + (size_t)(bn + r8) * 1024 + swe;
  const short* gv = BT + (size_t)(1024 + bn + r8) * 1024 + swe;
  short* lA = &As[0][0] + w * 512;   // wave-uniform base; HW adds lane*16B
  short* lq = &Bqs[0][0] + w * 512;
  short* lv = &Bvs[0][0] + w * 512;

  // full-tile stage (prologue only)
#define QV_STAGE(k, s) do {                                             \
    const short* a_ = gA + (k) * 64; short* la_ = lA + (s) * 16384;     \
    GLDS(a_, la_);               GLDS(a_ + 64 * 1024, la_ + 4096);      \
    GLDS(a_ + 128 * 1024, la_ + 8192); GLDS(a_ + 192 * 1024, la_ + 12288); \
    const short* q_ = gq + (k) * 64; short* lq_ = lq + (s) * 8192;      \
    GLDS(q_, lq_);               GLDS(q_ + 64 * 1024, lq_ + 4096);      \
    const short* v_ = gv + (k) * 64; short* lv_ = lv + (s) * 8192;      \
    GLDS(v_, lv_);               GLDS(v_ + 64 * 1024, lv_ + 4096);      \
  } while (0)

  const int csw0 = (quad ^ (l16 & 7)) * 8;        // k-chunk quad   (k-half 0)
  const int csw1 = ((quad + 4) ^ (l16 & 7)) * 8;  // k-chunk quad+4 (k-half 1)
  const short* fA0 = &As[0][0] + (wm + l16) * 64 + csw0;
  const short* fA1 = &As[0][0] + (wm + l16) * 64 + csw1;
  const short* fq0 = &Bqs[0][0] + (wn + l16) * 64 + csw0;
  const short* fq1 = &Bqs[0][0] + (wn + l16) * 64 + csw1;
  const short* fv0 = &Bvs[0][0] + (wn + l16) * 64 + csw0;
  const short* fv1 = &Bvs[0][0] + (wn + l16) * 64 + csw1;

  f32x4 aq[4][4] = {};
  f32x4 av[4][4] = {};

  QV_STAGE(0, 0);
  QV_STAGE(1, 1);

  for (int j = 0; j < 16; ++j) {
    const int s = j & 1;
    const short* sA0 = fA0 + s * 16384;
    const short* sA1 = fA1 + s * 16384;
    const short* sq0 = fq0 + s * 8192;
    const short* sq1 = fq1 + s * 8192;
    const short* sv0 = fv0 + s * 8192;
    const short* sv1 = fv1 + s * 8192;

    // tile j landed iff only tile j+1's 8 loads remain (in-order retirement)
    if (j < 15) { VMCNT(8); } else { VMCNT(0); }
    BAR();

    bf16x8 a0[4], a1[4], bq0[4], bq1[4], bv0[4], bv1[4];
    // ---- ph0: read A (both k-halves) + Bq k-half0 (12 reads); MFMA q k0 ----
#pragma unroll
    for (int i = 0; i < 4; ++i) {
      a0[i] = *(const bf16x8*)(sA0 + i * 1024);
      a1[i] = *(const bf16x8*)(sA1 + i * 1024);
      bq0[i] = *(const bf16x8*)(sq0 + i * 1024);
    }
    BAR(); LGKM0(); SCHED0(); PRIO(1);
#pragma unroll
    for (int i = 0; i < 4; ++i)
#pragma unroll
      for (int n = 0; n < 4; ++n)
        aq[i][n] = MFMA(a0[i], bq0[n], aq[i][n]);
    PRIO(0); BAR();
    // ---- ph1: read Bq k1 + Bv k0 + Bv k1 (12 reads); MFMA q k1 ----
#pragma unroll
    for (int i = 0; i < 4; ++i) {
      bq1[i] = *(const bf16x8*)(sq1 + i * 1024);
      bv0[i] = *(const bf16x8*)(sv0 + i * 1024);
      bv1[i] = *(const bf16x8*)(sv1 + i * 1024);
    }
    BAR(); LGKM0(); SCHED0(); PRIO(1);
#pragma unroll
    for (int i = 0; i < 4; ++i)
#pragma unroll
      for (int n = 0; n < 4; ++n)
        aq[i][n] = MFMA(a1[i], bq1[n], aq[i][n]);
    PRIO(0); BAR();
    // slot s fully consumed chip-wide -> staging tile j+2 into s is race-free.
    // ---- ph2: GLDS A of tile j+2 (4) interleaved with MFMA v k0 ----
    if (j < 14) {
      const short* a_ = gA + (j + 2) * 64; short* la_ = lA + s * 16384;
      GLDS(a_, la_);                     GLDS(a_ + 64 * 1024, la_ + 4096);
      GLDS(a_ + 128 * 1024, la_ + 8192); GLDS(a_ + 192 * 1024, la_ + 12288);
    }
    PRIO(1);
#pragma unroll
    for (int i = 0; i < 4; ++i)
#pragma unroll
      for (int n = 0; n < 4; ++n)
        av[i][n] = MFMA(a0[i], bv0[n], av[i][n]);
    PRIO(0); BAR();
    // ---- ph3: GLDS Bq,Bv of tile j+2 (4) interleaved with MFMA v k1 ----
    if (j < 14) {
      const short* q_ = gq + (j + 2) * 64; short* lq_ = lq + s * 8192;
      GLDS(q_, lq_); GLDS(q_ + 64 * 1024, lq_ + 4096);
      const short* v_ = gv + (j + 2) * 64; short* lv_ = lv + s * 8192;
      GLDS(v_, lv_); GLDS(v_ + 64 * 1024, lv_ + 4096);
    }
    PRIO(1);
#pragma unroll
    for (int i = 0; i < 4; ++i)
#pragma unroll
      for (int n = 0; n < 4; ++n)
        av[i][n] = MFMA(a1[i], bv1[n], av[i][n]);
    PRIO(0); BAR();
  }
#undef QV_STAGE

  // epilogue: C/D layout col=lane&15, row=(lane>>4)*4+reg  [m89/m91-verified]
#pragma unroll
  for (int n = 0; n < 4; ++n) {
    const int col = bn + wn + n * 16 + l16;
    const float bql = bq[col], bvl = bv[col];
#pragma unroll
    for (int i = 0; i < 4; ++i)
#pragma unroll
      for (int r = 0; r < 4; ++r) {
        const int row = bm + wm + i * 16 + quad * 4 + r;
        const float q = aq[i][n][r] + bql;
        const float v = av[i][n][r] + bvl;
        const float sg = 1.0f / (1.0f + __expf(-q));
        X[(size_t)row * 1024 + col] = f2bf(sg * v);
      }
  }
}

// ---- Phase 2: out = X @ WoT^T + bo, fp32. R0-proven structure: 128x128 tile,
// BK=64, 256 thr (4 waves 2x2, wave 64x64), 32 KiB LDS, grid (64,8) = 512
// blocks = 2 blocks/CU. Inter-block TLP hides the staging drain. ----
__global__ __launch_bounds__(256) void gemm_bt_kernel(
    const short* __restrict__ A, const short* __restrict__ BT, float* __restrict__ C,
    const float* __restrict__ bias) {
  __shared__ short As[128 * 64];  // 16 KiB
  __shared__ short Bs[128 * 64];  // 16 KiB
  const int t = threadIdx.x;
  const int lane = t & 63;
  const int w = t >> 6;
  const int l16 = lane & 15;
  const int quad = lane >> 4;
  const int bm = blockIdx.x * 128;
  const int bn = blockIdx.y * 128;
  const int wm = (w & 1) * 64;
  const int wn = (w >> 1) * 64;

  const int r8 = t >> 3;
  const int swe = ((t & 7) ^ (r8 & 7)) * 8;
  const short* pA0 = A + (size_t)(bm + r8) * 1024 + swe;
  const short* pA1 = pA0 + 32 * 1024;
  const short* pA2 = pA0 + 64 * 1024;
  const short* pA3 = pA0 + 96 * 1024;
  const short* pB0 = BT + (size_t)(bn + r8) * 1024 + swe;
  const short* pB1 = pB0 + 32 * 1024;
  const short* pB2 = pB0 + 64 * 1024;
  const short* pB3 = pB0 + 96 * 1024;
  short* lA = As + w * 512;
  short* lB = Bs + w * 512;

  const int qsw0 = (quad ^ (l16 & 7)) * 8;
  const int qsw1 = ((quad + 4) ^ (l16 & 7)) * 8;
  const short* fA0 = As + (wm + l16) * 64 + qsw0;
  const short* fA1 = As + (wm + l16) * 64 + qsw1;
  const short* fB0 = Bs + (wn + l16) * 64 + qsw0;
  const short* fB1 = Bs + (wn + l16) * 64 + qsw1;

  f32x4 acc[4][4] = {};

  for (int it = 0; it < 16; ++it) {
    GLDS(pA0, lA); GLDS(pA1, lA + 2048); GLDS(pA2, lA + 4096); GLDS(pA3, lA + 6144);
    GLDS(pB0, lB); GLDS(pB1, lB + 2048); GLDS(pB2, lB + 4096); GLDS(pB3, lB + 6144);
    pA0 += 64; pA1 += 64; pA2 += 64; pA3 += 64;
    pB0 += 64; pB1 += 64; pB2 += 64; pB3 += 64;
    __syncthreads();

#pragma unroll
    for (int h = 0; h < 2; h++) {
      const short* fA = h ? fA1 : fA0;
      const short* fB = h ? fB1 : fB0;
      bf16x8 av[4], bw[4];
#pragma unroll
      for (int i = 0; i < 4; i++) av[i] = *(const bf16x8*)(fA + i * 1024);
#pragma unroll
      for (int j = 0; j < 4; j++) bw[j] = *(const bf16x8*)(fB + j * 1024);
#pragma unroll
      for (int i = 0; i < 4; i++)
#pragma unroll
        for (int j = 0; j < 4; j++)
          acc[i][j] = MFMA(av[i], bw[j], acc[i][j]);
    }
    __syncthreads();
  }

#pragma unroll
  for (int j = 0; j < 4; j++) {
    int col = bn + wn + j * 16 + l16;
    float bl = bias[col];
#pragma unroll
    for (int i = 0; i < 4; i++)
#pragma unroll
      for (int r = 0; r < 4; r++) {
        int row = bm + wm + i * 16 + quad * 4 + r;
        C[(size_t)row * 1024 + col] = acc[i][j][r] + bl;
      }
  }
}

extern "C" void kernel_launch(void* const* d_in, const int* in_sizes, int n_in,
                              void* d_out, int out_size, void* d_ws, size_t ws_size,
                              hipStream_t stream) {
  const float* emb = (const float*)d_in[0];
  const float* Wq  = (const float*)d_in[1];
  const float* bq  = (const float*)d_in[2];
  // d_in[3]=Wk, d_in[4]=bk, d_in[7]=w are mathematically dead (they cancel)
  const float* Wv  = (const float*)d_in[5];
  const float* bv  = (const float*)d_in[6];
  const float* Wo  = (const float*)d_in[8];
  const float* bo  = (const float*)d_in[9];
  float* out = (float*)d_out;

  // workspace layout (bytes)
  char* ws = (char*)d_ws;
  short* embB = (short*)(ws);                 // 8192*1024 bf16 = 16 MiB
  short* X    = (short*)(ws + 16777216);      // 8192*1024 bf16 = 16 MiB
  short* WqvT = (short*)(ws + 33554432);      // [WqT | WvT] 2048*1024 = 4 MiB
  short* WoT  = (short*)(ws + 37748736);      // 1024*1024 = 2 MiB
  // total: 39,845,888 bytes

  prep_kernel<<<768, 256, 0, stream>>>(emb, Wq, Wv, Wo, embB, WqvT, WoT);
  gemm_qv_kernel<<<256, 512, 0, stream>>>(embB, WqvT, bq, bv, X);
  gemm_bt_kernel<<<dim3(64, 8), 256, 0, stream>>>(X, WoT, out, bo);
}